// Round 6
// baseline (325.962 us; speedup 1.0000x reference)
//
#include <hip/hip_runtime.h>
#include <math.h>

typedef unsigned short u16;
typedef __attribute__((ext_vector_type(8))) short short8;
typedef __bf16 bf16x8 __attribute__((ext_vector_type(8)));
typedef __attribute__((ext_vector_type(4))) float float4v;

#define BB 2
#define AA 512
#define TT 512
#define FF 128
#define NRBF 25
#define TROWS 32            // t-rows per main-loop iteration
#define NIT (TT / TROWS)    // 16

// static device scratch for y = x @ Win (fp32)
__device__ float g_y[BB * AA * FF];

__device__ __forceinline__ float bf2f(u16 u) {
    unsigned int v = ((unsigned int)u) << 16;
    return __builtin_bit_cast(float, v);
}
__device__ __forceinline__ u16 f2bf(float f) {
    unsigned int u = __builtin_bit_cast(unsigned int, f);
    u += 0x7fffu + ((u >> 16) & 1u);   // RNE
    return (u16)(u >> 16);
}
// shifted softplus — ocml path (round-3 verified: absmax 0.125).
// hw exp2/log2 versions measured +0.5 absmax (r4/r5); keep ocml until the
// hw-ssp error mechanism is understood.
__device__ __forceinline__ float ssp(float v) {
    float a = fabsf(v);
    return fmaxf(v, 0.0f) + log1pf(expf(-a)) - 0.69314718055994530942f;
}
__device__ __forceinline__ float4v mfma16(short8 a, short8 b, float4v c) {
    return __builtin_amdgcn_mfma_f32_16x16x32_bf16(
        __builtin_bit_cast(bf16x8, a), __builtin_bit_cast(bf16x8, b), c, 0, 0, 0);
}

// ---------------- kernel 1: y[b,a,f] = sum_i x[b,a,i] * Win[i,f] -------------
__global__ __launch_bounds__(128) void k_in2f(const float* __restrict__ x,
                                              const float* __restrict__ Win) {
    int ba = blockIdx.x;
    int o  = threadIdx.x;
    __shared__ float sx[FF];
    sx[o] = x[ba * FF + o];
    __syncthreads();
    float s = 0.f;
#pragma unroll 8
    for (int i = 0; i < FF; ++i)
        s = fmaf(sx[i], Win[i * FF + o], s);
    g_y[ba * FF + o] = s;
}

// ---------------- kernel 2: fused filter-net + gather-product + output -------
__global__ __launch_bounds__(256) void k_main(
    const float* __restrict__ r_ij, const float* __restrict__ mask,
    const float* __restrict__ Wf1,  const float* __restrict__ bf1,
    const float* __restrict__ Wf2,  const float* __restrict__ bf2_,
    const float* __restrict__ Wout, const float* __restrict__ bout,
    const int* __restrict__ nbrj,   const int* __restrict__ nbrk,
    float* __restrict__ out)
{
    const int ba  = blockIdx.x;
    const int tid = threadIdx.x;
    const int w   = tid >> 6;
    const int l   = tid & 63;
    const int lm  = l & 15;
    const int lq  = l >> 4;

    __shared__ __align__(16) u16 sR[TROWS][40];    // K padded to 32 (+row pad)
    __shared__ __align__(16) u16 sH1[TROWS][136];  // H1 tile bf16, row pad +8
    __shared__ int   sJ[TROWS];
    __shared__ int   sK[TROWS];
    __shared__ float sM[TROWS];
    __shared__ float sAcc[FF];

    // zero the K-pad columns [25,32) once; staging never touches them
    if (tid < TROWS * 7) {
        int tt = tid / 7, k = 25 + tid % 7;
        sR[tt][k] = 0;
    }

    // ---- preload constant B-fragments (bf16) ----
    short8 fWf1[2];
    short8 fWf2[4][2];
    float  bf1v[2], bf2v[2];
#pragma unroll
    for (int q = 0; q < 2; ++q) {
        const int n = 32 * w + 16 * q + lm;
        short8 v;
#pragma unroll
        for (int j = 0; j < 8; ++j) {
            const int k = lq * 8 + j;
            v[j] = (k < NRBF) ? (short)f2bf(Wf1[k * FF + n]) : (short)0;
        }
        fWf1[q] = v;
        bf1v[q] = bf1[n];
        bf2v[q] = bf2_[n];
#pragma unroll
        for (int kk = 0; kk < 4; ++kk) {
            short8 u;
#pragma unroll
            for (int j = 0; j < 8; ++j)
                u[j] = (short)f2bf(Wf2[(kk * 32 + lq * 8 + j) * FF + n]);
            fWf2[kk][q] = u;
        }
    }

    const float* yb = g_y + (ba >> 9) * (AA * FF);
    const float4v zero = {0.f, 0.f, 0.f, 0.f};
    float acc[2] = {0.f, 0.f};

    // ---- register double-buffer: prefetch tile 0 ----
    float pr[4]; int pjk = 0; float pmv = 0.f;
    {
        const float* rb = r_ij + (ba * TT + 0) * NRBF;
        pr[0] = rb[tid]; pr[1] = rb[tid + 256]; pr[2] = rb[tid + 512];
        if (tid < 32) pr[3] = rb[tid + 768];
        if (tid < 64)      pjk = (tid < 32 ? nbrj : nbrk - 32)[ba * TT + tid];
        else if (tid < 96) pmv = mask[ba * TT + (tid - 64)];
    }

    for (int tile = 0; tile < NIT; ++tile) {
        __syncthreads();                       // (a) prev-iter LDS reads done
        // ---- staged regs -> LDS (bf16) ----
#pragma unroll
        for (int jj = 0; jj < 3; ++jj) {
            int idx = tid + 256 * jj;
            int tt = (idx * 5243) >> 17;       // idx/25 for idx<800
            int k  = idx - tt * 25;
            sR[tt][k] = f2bf(pr[jj]);
        }
        if (tid < 32) {
            int idx = tid + 768;
            int tt = (idx * 5243) >> 17;
            int k  = idx - tt * 25;
            sR[tt][k] = f2bf(pr[3]);
            sJ[tid] = pjk & (AA - 1);
        } else if (tid < 64) {
            sK[tid - 32] = pjk & (AA - 1);
        } else if (tid < 96) {
            sM[tid - 64] = pmv;
        }
        __syncthreads();                       // (b) staging visible

        // ---- prefetch next tile into regs (latency hidden by phases A/B) ----
        {
            int nt = (tile + 1 < NIT) ? tile + 1 : tile;
            const float* rb = r_ij + (ba * TT + nt * TROWS) * NRBF;
            pr[0] = rb[tid]; pr[1] = rb[tid + 256]; pr[2] = rb[tid + 512];
            if (tid < 32) pr[3] = rb[tid + 768];
            if (tid < 64)      pjk = (tid < 32 ? nbrj : nbrk - 32)[ba * TT + nt * TROWS + tid];
            else if (tid < 96) pmv = mask[ba * TT + nt * TROWS + (tid - 64)];
        }

        // ---- early-issue phase-C gathers (overlap with A/B compute) ----
        float mi[2][4];
        float gj[2][2][4], gk[2][2][4];
#pragma unroll
        for (int mf = 0; mf < 2; ++mf)
#pragma unroll
            for (int r = 0; r < 4; ++r) {
                int m = mf * 16 + lq * 4 + r;
                int jv = sJ[m], kv = sK[m];
                mi[mf][r] = sM[m];
#pragma unroll
                for (int q = 0; q < 2; ++q) {
                    int n = 32 * w + 16 * q + lm;
                    gj[mf][q][r] = yb[jv * FF + n];
                    gk[mf][q][r] = yb[kv * FF + n];
                }
            }

        // ---- phase A: H1 = ssp(R @ Wf1 + bf1) ----
        float4v c1[2][2];
#pragma unroll
        for (int mf = 0; mf < 2; ++mf) {
            short8 aR = *(const short8*)((const char*)&sR[0][0] + (mf * 16 + lm) * 80 + lq * 16);
#pragma unroll
            for (int q = 0; q < 2; ++q)
                c1[mf][q] = mfma16(aR, fWf1[q], zero);
        }
#pragma unroll
        for (int mf = 0; mf < 2; ++mf)
#pragma unroll
            for (int q = 0; q < 2; ++q) {
                const int n = 32 * w + 16 * q + lm;
#pragma unroll
                for (int r = 0; r < 4; ++r) {
                    const int m = mf * 16 + lq * 4 + r;
                    sH1[m][n] = f2bf(ssp(c1[mf][q][r] + bf1v[q]));
                }
            }
        __syncthreads();                       // (c) H1 visible

        // ---- phase B: H2 = H1 @ Wf2 ----
        float4v c2[2][2] = {{zero, zero}, {zero, zero}};
#pragma unroll
        for (int mf = 0; mf < 2; ++mf)
#pragma unroll
            for (int kk = 0; kk < 4; ++kk) {
                short8 aH = *(const short8*)((const char*)&sH1[0][0] + (mf * 16 + lm) * 272 + kk * 64 + lq * 16);
#pragma unroll
                for (int q = 0; q < 2; ++q)
                    c2[mf][q] = mfma16(aH, fWf2[kk][q], c2[mf][q]);
            }

        // ---- phase C: acc[f] += (H2+bf2) * y_j * y_k * mask ----
#pragma unroll
        for (int mf = 0; mf < 2; ++mf)
#pragma unroll
            for (int q = 0; q < 2; ++q) {
                float s = 0.f;
#pragma unroll
                for (int r = 0; r < 4; ++r) {
                    float h2 = c2[mf][q][r] + bf2v[q];
                    s = fmaf(h2 * gj[mf][q][r], gk[mf][q][r] * mi[mf][r], s);
                }
                acc[q] += s;
            }
    }

    // ---- reduce over quads, publish acc ----
#pragma unroll
    for (int q = 0; q < 2; ++q) {
        float v = acc[q];
        v += __shfl_xor(v, 16);
        v += __shfl_xor(v, 32);
        if (lq == 0) sAcc[32 * w + 16 * q + lm] = v;
    }
    __syncthreads();

    // ---- epilogue: out = ssp(acc @ Wout + bout) ----
    if (tid < FF) {
        float s = bout[tid];
#pragma unroll 8
        for (int f = 0; f < FF; ++f)
            s = fmaf(sAcc[f], Wout[f * FF + tid], s);
        out[ba * FF + tid] = ssp(s);
    }
}

extern "C" void kernel_launch(void* const* d_in, const int* in_sizes, int n_in,
                              void* d_out, int out_size, void* d_ws, size_t ws_size,
                              hipStream_t stream) {
    const float* x    = (const float*)d_in[0];
    const float* r_ij = (const float*)d_in[1];
    const float* mask = (const float*)d_in[2];
    const float* Wf1  = (const float*)d_in[3];
    const float* bf1  = (const float*)d_in[4];
    const float* Wf2  = (const float*)d_in[5];
    const float* bf2  = (const float*)d_in[6];
    const float* Win  = (const float*)d_in[7];
    const float* Wout = (const float*)d_in[8];
    const float* bout = (const float*)d_in[9];
    const int* nj     = (const int*)d_in[10];
    const int* nk     = (const int*)d_in[11];
    float* out = (float*)d_out;
    (void)d_ws; (void)ws_size; (void)in_sizes; (void)n_in; (void)out_size;

    k_in2f<<<BB * AA, 128, 0, stream>>>(x, Win);
    k_main<<<BB * AA, 256, 0, stream>>>(r_ij, mask, Wf1, bf1, Wf2, bf2,
                                        Wout, bout, nj, nk, out);
}